// Round 14
// baseline (196.718 us; speedup 1.0000x reference)
//
#include <hip/hip_runtime.h>

#define RES 128
#define NCELLS (RES * RES * RES)        // 2097152
#define CASC 4
#define GRID_TOTAL (CASC * NCELLS)      // 8388608
#define NBYTES (GRID_TOTAL / 8)         // 1048576
#define PTS 4
#define MAIN_BLOCKS (NCELLS / (256 * PTS))   // 2048

typedef float f32x2 __attribute__((ext_vector_type(2)));

// inverse of instant-ngp expand_bits: gather every 3rd bit
__device__ __forceinline__ unsigned compact3(unsigned v) {
    v &= 0x49249249u;
    v = (v | (v >> 2))  & 0xC30C30C3u;
    v = (v | (v >> 4))  & 0x0F00F00Fu;
    v = (v | (v >> 8))  & 0xFF0000FFu;
    v = (v | (v >> 16)) & 0x3FFu;
    return v;
}

__device__ __forceinline__ f32x2 pk_fma(f32x2 a, f32x2 b, f32x2 c) {
    return __builtin_elementwise_fma(a, b, c);   // v_pk_fma_f32, IEEE fma per lane
}

// 2048 blocks x 256 threads x 4 morton points, phase-split by hand:
// phase A issues ALL 64 global loads (named scalars), sched_barrier(0) pins
// the schedule, phase B computes 4 points sequentially. Goal: R11's 4-deep
// load ILP at ~110 VGPR instead of the compiler's 184 -> 2x residency.
__global__ __launch_bounds__(256) void dg_main(
    const float* __restrict__ dgrid,   // [CASC, NCELLS]
    const float* __restrict__ jit,     // [CASC, NCELLS, 3]
    const float* __restrict__ W1,      // [3,32]
    const float* __restrict__ b1,      // [32]
    const float* __restrict__ W2,      // [32]
    const float* __restrict__ b2,      // [1]
    float* __restrict__ out,           // [CASC, NCELLS]
    double* __restrict__ sum_ws)
{
    // wq[j] = {W1[j], W1[32+j], W1[64+j], b1[j]};  w2s[j] = W2[j]
    __shared__ float4 wq[32];
    __shared__ float w2s[32];
    __shared__ double sdata[4];
    if (threadIdx.x < 32) {
        const int j = threadIdx.x;
        wq[j] = make_float4(W1[j], W1[32 + j], W1[64 + j], b1[j]);
        w2s[j] = W2[j];
    }
    __syncthreads();

    const float bb2 = b2[0];
    const int tid = (int)threadIdx.x;
    const int mbase = blockIdx.x * (256 * PTS);

    // ---- phase A: all addresses + all 64 global loads, named scalars ----
#define LOADPT(K) \
    const int m_##K = mbase + K * 256 + tid; \
    const unsigned x_##K = compact3((unsigned)m_##K); \
    const unsigned y_##K = compact3((unsigned)m_##K >> 1); \
    const unsigned z_##K = compact3((unsigned)m_##K >> 2); \
    const size_t jb_##K = ((size_t)((x_##K << 14) | (y_##K << 7) | z_##K)) * 3; \
    const float jA_##K = jit[jb_##K + 0]; \
    const float jB_##K = jit[jb_##K + 1]; \
    const float jC_##K = jit[jb_##K + 2]; \
    const float jD_##K = jit[(size_t)NCELLS * 3 + jb_##K + 0]; \
    const float jE_##K = jit[(size_t)NCELLS * 3 + jb_##K + 1]; \
    const float jF_##K = jit[(size_t)NCELLS * 3 + jb_##K + 2]; \
    const float jG_##K = jit[(size_t)NCELLS * 6 + jb_##K + 0]; \
    const float jH_##K = jit[(size_t)NCELLS * 6 + jb_##K + 1]; \
    const float jI_##K = jit[(size_t)NCELLS * 6 + jb_##K + 2]; \
    const float jJ_##K = jit[(size_t)NCELLS * 9 + jb_##K + 0]; \
    const float jK_##K = jit[(size_t)NCELLS * 9 + jb_##K + 1]; \
    const float jL_##K = jit[(size_t)NCELLS * 9 + jb_##K + 2]; \
    const float g0_##K = dgrid[(size_t)m_##K]; \
    const float g1_##K = dgrid[(size_t)NCELLS + m_##K]; \
    const float g2_##K = dgrid[(size_t)2 * NCELLS + m_##K]; \
    const float g3_##K = dgrid[(size_t)3 * NCELLS + m_##K];

    LOADPT(0) LOADPT(1) LOADPT(2) LOADPT(3)
#undef LOADPT

    __builtin_amdgcn_sched_barrier(0);   // nothing crosses: loads stay hoisted

    double lsum = 0.0;

    // ---- phase B: compute 4 points sequentially (R10/R11 body, same order) ----
#define COMPPT(K) { \
    const float cx = (float)x_##K, cy = (float)y_##K, cz = (float)z_##K; \
    const float px0 = ((cx + jA_##K) * (1.0f / 128.0f) - 0.5f) * 1.0f; \
    const float py0 = ((cy + jB_##K) * (1.0f / 128.0f) - 0.5f) * 1.0f; \
    const float pz0 = ((cz + jC_##K) * (1.0f / 128.0f) - 0.5f) * 1.0f; \
    const float px1 = ((cx + jD_##K) * (1.0f / 128.0f) - 0.5f) * 2.0f; \
    const float py1 = ((cy + jE_##K) * (1.0f / 128.0f) - 0.5f) * 2.0f; \
    const float pz1 = ((cz + jF_##K) * (1.0f / 128.0f) - 0.5f) * 2.0f; \
    const float px2 = ((cx + jG_##K) * (1.0f / 128.0f) - 0.5f) * 4.0f; \
    const float py2 = ((cy + jH_##K) * (1.0f / 128.0f) - 0.5f) * 4.0f; \
    const float pz2 = ((cz + jI_##K) * (1.0f / 128.0f) - 0.5f) * 4.0f; \
    const float px3 = ((cx + jJ_##K) * (1.0f / 128.0f) - 0.5f) * 8.0f; \
    const float py3 = ((cy + jK_##K) * (1.0f / 128.0f) - 0.5f) * 8.0f; \
    const float pz3 = ((cz + jL_##K) * (1.0f / 128.0f) - 0.5f) * 8.0f; \
    const f32x2 pxA = {px0, px1}, pxB = {px2, px3}; \
    const f32x2 pyA = {py0, py1}, pyB = {py2, py3}; \
    const f32x2 pzA = {pz0, pz1}, pzB = {pz2, pz3}; \
    const f32x2 zer = {0.0f, 0.0f}; \
    f32x2 accA = {bb2, bb2}, accB = {bb2, bb2}; \
    _Pragma("unroll") \
    for (int j = 0; j < 32; ++j) { \
        const float4 w = wq[j]; \
        const float u = w2s[j]; \
        const f32x2 wx = {w.x, w.x}, wy = {w.y, w.y}, wz = {w.z, w.z}; \
        const f32x2 wb = {w.w, w.w}, uu = {u, u}; \
        f32x2 hA = pk_fma(pxA, wx, wb); \
        f32x2 hB = pk_fma(pxB, wx, wb); \
        hA = pk_fma(pyA, wy, hA); \
        hB = pk_fma(pyB, wy, hB); \
        hA = pk_fma(pzA, wz, hA); \
        hB = pk_fma(pzB, wz, hB); \
        hA = __builtin_elementwise_max(hA, zer); \
        hB = __builtin_elementwise_max(hB, zer); \
        accA = pk_fma(hA, uu, accA); \
        accB = pk_fma(hB, uu, accB); \
    } \
    { const float a0 = accA.x; \
      const float d0 = fmaxf(a0, 0.0f) + log1pf(expf(-fabsf(a0))); \
      const float n0 = (g0_##K >= 0.0f && d0 >= 0.0f) ? fmaxf(g0_##K * 0.95f, d0) : g0_##K; \
      out[(size_t)m_##K] = n0; lsum += (double)n0; \
      const float a1 = accA.y; \
      const float d1 = fmaxf(a1, 0.0f) + log1pf(expf(-fabsf(a1))); \
      const float n1 = (g1_##K >= 0.0f && d1 >= 0.0f) ? fmaxf(g1_##K * 0.95f, d1) : g1_##K; \
      out[(size_t)NCELLS + m_##K] = n1; lsum += (double)n1; \
      const float a2 = accB.x; \
      const float d2 = fmaxf(a2, 0.0f) + log1pf(expf(-fabsf(a2))); \
      const float n2 = (g2_##K >= 0.0f && d2 >= 0.0f) ? fmaxf(g2_##K * 0.95f, d2) : g2_##K; \
      out[(size_t)2 * NCELLS + m_##K] = n2; lsum += (double)n2; \
      const float a3 = accB.y; \
      const float d3 = fmaxf(a3, 0.0f) + log1pf(expf(-fabsf(a3))); \
      const float n3 = (g3_##K >= 0.0f && d3 >= 0.0f) ? fmaxf(g3_##K * 0.95f, d3) : g3_##K; \
      out[(size_t)3 * NCELLS + m_##K] = n3; lsum += (double)n3; } }

    COMPPT(0) COMPPT(1) COMPPT(2) COMPPT(3)
#undef COMPPT

    // wave-level f64 reduction -> 4 LDS partials -> one atomic per block
    #pragma unroll
    for (int s = 32; s > 0; s >>= 1) lsum += __shfl_down(lsum, s);
    const int wid = threadIdx.x >> 6;
    const int lane = threadIdx.x & 63;
    if (lane == 0) sdata[wid] = lsum;
    __syncthreads();
    if (threadIdx.x == 0)
        atomicAdd(sum_ws, (sdata[0] + sdata[1]) + (sdata[2] + sdata[3]));
}

__global__ void dg_finalize(const double* __restrict__ sum_ws,
                            float* __restrict__ out,
                            float* __restrict__ thr_ws)
{
    const double mean = *sum_ws / (double)GRID_TOTAL;
    const float mf = (float)mean;
    out[GRID_TOTAL] = mf;                 // mean_density output
    *thr_ws = fminf(mf, 2.0f);            // thresh for bitfield pass
}

// One thread per output byte: read 8 consecutive grid floats, pack bits, emit as float.
__global__ __launch_bounds__(256) void dg_bitfield(
    const float* __restrict__ grid,
    const float* __restrict__ thr_ws,
    float* __restrict__ outb)
{
    const int i = blockIdx.x * 256 + threadIdx.x;
    const float t = *thr_ws;
    const float4* p = (const float4*)(grid + (size_t)i * 8);
    const float4 a = p[0];
    const float4 b = p[1];
    int v = 0;
    v |= (a.x > t) ? 1   : 0;
    v |= (a.y > t) ? 2   : 0;
    v |= (a.z > t) ? 4   : 0;
    v |= (a.w > t) ? 8   : 0;
    v |= (b.x > t) ? 16  : 0;
    v |= (b.y > t) ? 32  : 0;
    v |= (b.z > t) ? 64  : 0;
    v |= (b.w > t) ? 128 : 0;
    outb[i] = (float)v;
}

extern "C" void kernel_launch(void* const* d_in, const int* in_sizes, int n_in,
                              void* d_out, int out_size, void* d_ws, size_t ws_size,
                              hipStream_t stream) {
    const float* dgrid = (const float*)d_in[0];
    const float* jit   = (const float*)d_in[1];
    const float* W1    = (const float*)d_in[2];
    const float* b1    = (const float*)d_in[3];
    const float* W2    = (const float*)d_in[4];
    const float* b2    = (const float*)d_in[5];

    float* out = (float*)d_out;
    double* sum_ws = (double*)d_ws;
    float* thr_ws = (float*)((char*)d_ws + 8);

    hipMemsetAsync(d_ws, 0, 8, stream);   // zero the f64 accumulator (capture-safe)

    dg_main<<<MAIN_BLOCKS, 256, 0, stream>>>(dgrid, jit, W1, b1, W2, b2, out, sum_ws);
    dg_finalize<<<1, 1, 0, stream>>>(sum_ws, out, thr_ws);
    dg_bitfield<<<NBYTES / 256, 256, 0, stream>>>(out, thr_ws, out + GRID_TOTAL + 1);
}

// Round 15
// 78.538 us; speedup vs baseline: 2.5048x; 2.5048x over previous
//
#include <hip/hip_runtime.h>

#define RES 128
#define NCELLS (RES * RES * RES)        // 2097152
#define CASC 4
#define GRID_TOTAL (CASC * NCELLS)      // 8388608
#define NBYTES (GRID_TOTAL / 8)         // 1048576
#define MAIN_BLOCKS (NCELLS / (256 * 4))     // 2048 (4 consecutive morton/thread)

typedef float f32x2 __attribute__((ext_vector_type(2)));

// inverse of instant-ngp expand_bits: gather every 3rd bit
__device__ __forceinline__ unsigned compact3(unsigned v) {
    v &= 0x49249249u;
    v = (v | (v >> 2))  & 0xC30C30C3u;
    v = (v | (v >> 4))  & 0x0F00F00Fu;
    v = (v | (v >> 8))  & 0xFF0000FFu;
    v = (v | (v >> 16)) & 0x3FFu;
    return v;
}

__device__ __forceinline__ f32x2 pk_fma(f32x2 a, f32x2 b, f32x2 c) {
    return __builtin_elementwise_fma(a, b, c);   // v_pk_fma_f32, IEEE fma per lane
}

// 2048 blocks x 256 threads; thread gid handles morton m = gid*4 + {0,1,2,3}.
// dgrid reads and out writes become float4 (dwordx4); jitter stays 16x 12B
// scattered loads (R11's proven ILP). Per-cell arithmetic identical to R10/R11.
__global__ __launch_bounds__(256) void dg_main(
    const float* __restrict__ dgrid,   // [CASC, NCELLS]
    const float* __restrict__ jit,     // [CASC, NCELLS, 3]
    const float* __restrict__ W1,      // [3,32]
    const float* __restrict__ b1,      // [32]
    const float* __restrict__ W2,      // [32]
    const float* __restrict__ b2,      // [1]
    float* __restrict__ out,           // [CASC, NCELLS]
    double* __restrict__ sum_ws)
{
    // wq[j] = {W1[j], W1[32+j], W1[64+j], b1[j]};  w2s[j] = W2[j]
    __shared__ float4 wq[32];
    __shared__ float w2s[32];
    __shared__ double sdata[4];
    if (threadIdx.x < 32) {
        const int j = threadIdx.x;
        wq[j] = make_float4(W1[j], W1[32 + j], W1[64 + j], b1[j]);
        w2s[j] = W2[j];
    }
    __syncthreads();

    const float bb2 = b2[0];
    const int gid = blockIdx.x * 256 + (int)threadIdx.x;   // float4-group index
    const int m0 = gid * 4;

    // ---- coalesced float4 dgrid loads (one dwordx4 per cascade) ----
    const float4* dg4 = (const float4*)dgrid;
    const float4 g4_0 = dg4[(size_t)0 * (NCELLS / 4) + gid];
    const float4 g4_1 = dg4[(size_t)1 * (NCELLS / 4) + gid];
    const float4 g4_2 = dg4[(size_t)2 * (NCELLS / 4) + gid];
    const float4 g4_3 = dg4[(size_t)3 * (NCELLS / 4) + gid];

    double lsum = 0.0;
    float n0_0, n0_1, n0_2, n0_3;   // results: n<level>_<k>
    float n1_0, n1_1, n1_2, n1_3;
    float n2_0, n2_1, n2_2, n2_3;
    float n3_0, n3_1, n3_2, n3_3;

    // per-point body: K = point index (0..3), C = float4 component (x/y/z/w)
#define COMPPT(K, C) { \
    const int m = m0 + K; \
    const unsigned x = compact3((unsigned)m); \
    const unsigned y = compact3((unsigned)m >> 1); \
    const unsigned z = compact3((unsigned)m >> 2); \
    const size_t jb = ((size_t)((x << 14) | (y << 7) | z)) * 3; \
    const float cx = (float)x, cy = (float)y, cz = (float)z; \
    const float jx0 = jit[jb + 0], jy0 = jit[jb + 1], jz0 = jit[jb + 2]; \
    const float jx1 = jit[(size_t)NCELLS * 3 + jb + 0]; \
    const float jy1 = jit[(size_t)NCELLS * 3 + jb + 1]; \
    const float jz1 = jit[(size_t)NCELLS * 3 + jb + 2]; \
    const float jx2 = jit[(size_t)NCELLS * 6 + jb + 0]; \
    const float jy2 = jit[(size_t)NCELLS * 6 + jb + 1]; \
    const float jz2 = jit[(size_t)NCELLS * 6 + jb + 2]; \
    const float jx3 = jit[(size_t)NCELLS * 9 + jb + 0]; \
    const float jy3 = jit[(size_t)NCELLS * 9 + jb + 1]; \
    const float jz3 = jit[(size_t)NCELLS * 9 + jb + 2]; \
    const float px0 = ((cx + jx0) * (1.0f / 128.0f) - 0.5f) * 1.0f; \
    const float py0 = ((cy + jy0) * (1.0f / 128.0f) - 0.5f) * 1.0f; \
    const float pz0 = ((cz + jz0) * (1.0f / 128.0f) - 0.5f) * 1.0f; \
    const float px1 = ((cx + jx1) * (1.0f / 128.0f) - 0.5f) * 2.0f; \
    const float py1 = ((cy + jy1) * (1.0f / 128.0f) - 0.5f) * 2.0f; \
    const float pz1 = ((cz + jz1) * (1.0f / 128.0f) - 0.5f) * 2.0f; \
    const float px2 = ((cx + jx2) * (1.0f / 128.0f) - 0.5f) * 4.0f; \
    const float py2 = ((cy + jy2) * (1.0f / 128.0f) - 0.5f) * 4.0f; \
    const float pz2 = ((cz + jz2) * (1.0f / 128.0f) - 0.5f) * 4.0f; \
    const float px3 = ((cx + jx3) * (1.0f / 128.0f) - 0.5f) * 8.0f; \
    const float py3 = ((cy + jy3) * (1.0f / 128.0f) - 0.5f) * 8.0f; \
    const float pz3 = ((cz + jz3) * (1.0f / 128.0f) - 0.5f) * 8.0f; \
    const f32x2 pxA = {px0, px1}, pxB = {px2, px3}; \
    const f32x2 pyA = {py0, py1}, pyB = {py2, py3}; \
    const f32x2 pzA = {pz0, pz1}, pzB = {pz2, pz3}; \
    const f32x2 zer = {0.0f, 0.0f}; \
    f32x2 accA = {bb2, bb2}, accB = {bb2, bb2}; \
    _Pragma("unroll") \
    for (int j = 0; j < 32; ++j) { \
        const float4 w = wq[j]; \
        const float u = w2s[j]; \
        const f32x2 wx = {w.x, w.x}, wy = {w.y, w.y}, wz = {w.z, w.z}; \
        const f32x2 wb = {w.w, w.w}, uu = {u, u}; \
        f32x2 hA = pk_fma(pxA, wx, wb); \
        f32x2 hB = pk_fma(pxB, wx, wb); \
        hA = pk_fma(pyA, wy, hA); \
        hB = pk_fma(pyB, wy, hB); \
        hA = pk_fma(pzA, wz, hA); \
        hB = pk_fma(pzB, wz, hB); \
        hA = __builtin_elementwise_max(hA, zer); \
        hB = __builtin_elementwise_max(hB, zer); \
        accA = pk_fma(hA, uu, accA); \
        accB = pk_fma(hB, uu, accB); \
    } \
    { const float a0 = accA.x; \
      const float d0 = fmaxf(a0, 0.0f) + log1pf(expf(-fabsf(a0))); \
      const float g0 = g4_0.C; \
      n0_##K = (g0 >= 0.0f && d0 >= 0.0f) ? fmaxf(g0 * 0.95f, d0) : g0; \
      lsum += (double)n0_##K; \
      const float a1 = accA.y; \
      const float d1 = fmaxf(a1, 0.0f) + log1pf(expf(-fabsf(a1))); \
      const float g1 = g4_1.C; \
      n1_##K = (g1 >= 0.0f && d1 >= 0.0f) ? fmaxf(g1 * 0.95f, d1) : g1; \
      lsum += (double)n1_##K; \
      const float a2 = accB.x; \
      const float d2 = fmaxf(a2, 0.0f) + log1pf(expf(-fabsf(a2))); \
      const float g2 = g4_2.C; \
      n2_##K = (g2 >= 0.0f && d2 >= 0.0f) ? fmaxf(g2 * 0.95f, d2) : g2; \
      lsum += (double)n2_##K; \
      const float a3 = accB.y; \
      const float d3 = fmaxf(a3, 0.0f) + log1pf(expf(-fabsf(a3))); \
      const float g3 = g4_3.C; \
      n3_##K = (g3 >= 0.0f && d3 >= 0.0f) ? fmaxf(g3 * 0.95f, d3) : g3; \
      lsum += (double)n3_##K; } }

    COMPPT(0, x) COMPPT(1, y) COMPPT(2, z) COMPPT(3, w)
#undef COMPPT

    // ---- coalesced float4 stores (one dwordx4 per cascade) ----
    float4* o4 = (float4*)out;
    o4[(size_t)0 * (NCELLS / 4) + gid] = make_float4(n0_0, n0_1, n0_2, n0_3);
    o4[(size_t)1 * (NCELLS / 4) + gid] = make_float4(n1_0, n1_1, n1_2, n1_3);
    o4[(size_t)2 * (NCELLS / 4) + gid] = make_float4(n2_0, n2_1, n2_2, n2_3);
    o4[(size_t)3 * (NCELLS / 4) + gid] = make_float4(n3_0, n3_1, n3_2, n3_3);

    // wave-level f64 reduction -> 4 LDS partials -> one atomic per block
    #pragma unroll
    for (int s = 32; s > 0; s >>= 1) lsum += __shfl_down(lsum, s);
    const int wid = threadIdx.x >> 6;
    const int lane = threadIdx.x & 63;
    if (lane == 0) sdata[wid] = lsum;
    __syncthreads();
    if (threadIdx.x == 0)
        atomicAdd(sum_ws, (sdata[0] + sdata[1]) + (sdata[2] + sdata[3]));
}

__global__ void dg_finalize(const double* __restrict__ sum_ws,
                            float* __restrict__ out,
                            float* __restrict__ thr_ws)
{
    const double mean = *sum_ws / (double)GRID_TOTAL;
    const float mf = (float)mean;
    out[GRID_TOTAL] = mf;                 // mean_density output
    *thr_ws = fminf(mf, 2.0f);            // thresh for bitfield pass
}

// One thread per output byte: read 8 consecutive grid floats, pack bits, emit as float.
__global__ __launch_bounds__(256) void dg_bitfield(
    const float* __restrict__ grid,
    const float* __restrict__ thr_ws,
    float* __restrict__ outb)
{
    const int i = blockIdx.x * 256 + threadIdx.x;
    const float t = *thr_ws;
    const float4* p = (const float4*)(grid + (size_t)i * 8);
    const float4 a = p[0];
    const float4 b = p[1];
    int v = 0;
    v |= (a.x > t) ? 1   : 0;
    v |= (a.y > t) ? 2   : 0;
    v |= (a.z > t) ? 4   : 0;
    v |= (a.w > t) ? 8   : 0;
    v |= (b.x > t) ? 16  : 0;
    v |= (b.y > t) ? 32  : 0;
    v |= (b.z > t) ? 64  : 0;
    v |= (b.w > t) ? 128 : 0;
    outb[i] = (float)v;
}

extern "C" void kernel_launch(void* const* d_in, const int* in_sizes, int n_in,
                              void* d_out, int out_size, void* d_ws, size_t ws_size,
                              hipStream_t stream) {
    const float* dgrid = (const float*)d_in[0];
    const float* jit   = (const float*)d_in[1];
    const float* W1    = (const float*)d_in[2];
    const float* b1    = (const float*)d_in[3];
    const float* W2    = (const float*)d_in[4];
    const float* b2    = (const float*)d_in[5];

    float* out = (float*)d_out;
    double* sum_ws = (double*)d_ws;
    float* thr_ws = (float*)((char*)d_ws + 8);

    hipMemsetAsync(d_ws, 0, 8, stream);   // zero the f64 accumulator (capture-safe)

    dg_main<<<MAIN_BLOCKS, 256, 0, stream>>>(dgrid, jit, W1, b1, W2, b2, out, sum_ws);
    dg_finalize<<<1, 1, 0, stream>>>(sum_ws, out, thr_ws);
    dg_bitfield<<<NBYTES / 256, 256, 0, stream>>>(out, thr_ws, out + GRID_TOTAL + 1);
}

// Round 16
// 76.719 us; speedup vs baseline: 2.5641x; 1.0237x over previous
//
#include <hip/hip_runtime.h>

#define RES 128
#define NCELLS (RES * RES * RES)        // 2097152
#define CASC 4
#define GRID_TOTAL (CASC * NCELLS)      // 8388608
#define NBYTES (GRID_TOTAL / 8)         // 1048576
#define MAIN_BLOCKS (NCELLS / (256 * 4))     // 2048 (4 consecutive morton/thread)

typedef float f32x2 __attribute__((ext_vector_type(2)));

// inverse of instant-ngp expand_bits: gather every 3rd bit
__device__ __forceinline__ unsigned compact3(unsigned v) {
    v &= 0x49249249u;
    v = (v | (v >> 2))  & 0xC30C30C3u;
    v = (v | (v >> 4))  & 0x0F00F00Fu;
    v = (v | (v >> 8))  & 0xFF0000FFu;
    v = (v | (v >> 16)) & 0x3FFu;
    return v;
}

__device__ __forceinline__ f32x2 pk_fma(f32x2 a, f32x2 b, f32x2 c) {
    return __builtin_elementwise_fma(a, b, c);   // v_pk_fma_f32, IEEE fma per lane
}

// 2048 blocks x 256 threads; thread gid handles morton m = gid*4 + {0,1,2,3}.
// j-OUTER weight loop: each {wq[j], w2s[j]} LDS read feeds all 4 points
// (8 f32x2 chains) -> LDS reads per thread drop 256 -> 64 (the R15 LDS-pipe
// accounting: ~30us of ~65us was LDS throughput). Per-cell fma order identical.
__global__ __launch_bounds__(256) void dg_main(
    const float* __restrict__ dgrid,   // [CASC, NCELLS]
    const float* __restrict__ jit,     // [CASC, NCELLS, 3]
    const float* __restrict__ W1,      // [3,32]
    const float* __restrict__ b1,      // [32]
    const float* __restrict__ W2,      // [32]
    const float* __restrict__ b2,      // [1]
    float* __restrict__ out,           // [CASC, NCELLS]
    double* __restrict__ sum_ws)
{
    // wq[j] = {W1[j], W1[32+j], W1[64+j], b1[j]};  w2s[j] = W2[j]
    __shared__ float4 wq[32];
    __shared__ float w2s[32];
    __shared__ double sdata[4];
    if (threadIdx.x < 32) {
        const int j = threadIdx.x;
        wq[j] = make_float4(W1[j], W1[32 + j], W1[64 + j], b1[j]);
        w2s[j] = W2[j];
    }
    __syncthreads();

    const float bb2 = b2[0];
    const int gid = blockIdx.x * 256 + (int)threadIdx.x;   // float4-group index
    const int m0 = gid * 4;

    // ---- coalesced float4 dgrid loads (one dwordx4 per cascade) ----
    const float4* dg4 = (const float4*)dgrid;
    const float4 g4_0 = dg4[(size_t)0 * (NCELLS / 4) + gid];
    const float4 g4_1 = dg4[(size_t)1 * (NCELLS / 4) + gid];
    const float4 g4_2 = dg4[(size_t)2 * (NCELLS / 4) + gid];
    const float4 g4_3 = dg4[(size_t)3 * (NCELLS / 4) + gid];

    // ---- per-point coords, jitter loads, packed positions ----
#define PREP(K) \
    const int m_##K = m0 + K; \
    const unsigned x_##K = compact3((unsigned)m_##K); \
    const unsigned y_##K = compact3((unsigned)m_##K >> 1); \
    const unsigned z_##K = compact3((unsigned)m_##K >> 2); \
    const size_t jb_##K = ((size_t)((x_##K << 14) | (y_##K << 7) | z_##K)) * 3; \
    const float cx_##K = (float)x_##K, cy_##K = (float)y_##K, cz_##K = (float)z_##K; \
    const float jx0_##K = jit[jb_##K + 0], jy0_##K = jit[jb_##K + 1], jz0_##K = jit[jb_##K + 2]; \
    const float jx1_##K = jit[(size_t)NCELLS * 3 + jb_##K + 0]; \
    const float jy1_##K = jit[(size_t)NCELLS * 3 + jb_##K + 1]; \
    const float jz1_##K = jit[(size_t)NCELLS * 3 + jb_##K + 2]; \
    const float jx2_##K = jit[(size_t)NCELLS * 6 + jb_##K + 0]; \
    const float jy2_##K = jit[(size_t)NCELLS * 6 + jb_##K + 1]; \
    const float jz2_##K = jit[(size_t)NCELLS * 6 + jb_##K + 2]; \
    const float jx3_##K = jit[(size_t)NCELLS * 9 + jb_##K + 0]; \
    const float jy3_##K = jit[(size_t)NCELLS * 9 + jb_##K + 1]; \
    const float jz3_##K = jit[(size_t)NCELLS * 9 + jb_##K + 2]; \
    const f32x2 pxA_##K = { ((cx_##K + jx0_##K) * (1.0f / 128.0f) - 0.5f) * 1.0f, \
                            ((cx_##K + jx1_##K) * (1.0f / 128.0f) - 0.5f) * 2.0f }; \
    const f32x2 pxB_##K = { ((cx_##K + jx2_##K) * (1.0f / 128.0f) - 0.5f) * 4.0f, \
                            ((cx_##K + jx3_##K) * (1.0f / 128.0f) - 0.5f) * 8.0f }; \
    const f32x2 pyA_##K = { ((cy_##K + jy0_##K) * (1.0f / 128.0f) - 0.5f) * 1.0f, \
                            ((cy_##K + jy1_##K) * (1.0f / 128.0f) - 0.5f) * 2.0f }; \
    const f32x2 pyB_##K = { ((cy_##K + jy2_##K) * (1.0f / 128.0f) - 0.5f) * 4.0f, \
                            ((cy_##K + jy3_##K) * (1.0f / 128.0f) - 0.5f) * 8.0f }; \
    const f32x2 pzA_##K = { ((cz_##K + jz0_##K) * (1.0f / 128.0f) - 0.5f) * 1.0f, \
                            ((cz_##K + jz1_##K) * (1.0f / 128.0f) - 0.5f) * 2.0f }; \
    const f32x2 pzB_##K = { ((cz_##K + jz2_##K) * (1.0f / 128.0f) - 0.5f) * 4.0f, \
                            ((cz_##K + jz3_##K) * (1.0f / 128.0f) - 0.5f) * 8.0f }; \
    f32x2 accA_##K = {bb2, bb2}, accB_##K = {bb2, bb2};

    PREP(0) PREP(1) PREP(2) PREP(3)
#undef PREP

    const f32x2 zer = {0.0f, 0.0f};

    // ---- j-outer MLP: one weight fetch per j feeds 8 chains (16 cells) ----
#define STEP(K) { \
        f32x2 hA = pk_fma(pxA_##K, wx, wb); \
        f32x2 hB = pk_fma(pxB_##K, wx, wb); \
        hA = pk_fma(pyA_##K, wy, hA); \
        hB = pk_fma(pyB_##K, wy, hB); \
        hA = pk_fma(pzA_##K, wz, hA); \
        hB = pk_fma(pzB_##K, wz, hB); \
        hA = __builtin_elementwise_max(hA, zer); \
        hB = __builtin_elementwise_max(hB, zer); \
        accA_##K = pk_fma(hA, uu, accA_##K); \
        accB_##K = pk_fma(hB, uu, accB_##K); }

    #pragma unroll 4
    for (int j = 0; j < 32; ++j) {
        const float4 w = wq[j];
        const float u = w2s[j];
        const f32x2 wx = {w.x, w.x}, wy = {w.y, w.y}, wz = {w.z, w.z};
        const f32x2 wb = {w.w, w.w}, uu = {u, u};
        STEP(0) STEP(1) STEP(2) STEP(3)
    }
#undef STEP

    double lsum = 0.0;
    float n0_0, n0_1, n0_2, n0_3;   // results: n<level>_<k>
    float n1_0, n1_1, n1_2, n1_3;
    float n2_0, n2_1, n2_2, n2_3;
    float n3_0, n3_1, n3_2, n3_3;

#define TAIL(K, C) { \
    const float a0 = accA_##K.x; \
    const float d0 = fmaxf(a0, 0.0f) + log1pf(expf(-fabsf(a0))); \
    const float g0 = g4_0.C; \
    n0_##K = (g0 >= 0.0f && d0 >= 0.0f) ? fmaxf(g0 * 0.95f, d0) : g0; \
    lsum += (double)n0_##K; \
    const float a1 = accA_##K.y; \
    const float d1 = fmaxf(a1, 0.0f) + log1pf(expf(-fabsf(a1))); \
    const float g1 = g4_1.C; \
    n1_##K = (g1 >= 0.0f && d1 >= 0.0f) ? fmaxf(g1 * 0.95f, d1) : g1; \
    lsum += (double)n1_##K; \
    const float a2 = accB_##K.x; \
    const float d2 = fmaxf(a2, 0.0f) + log1pf(expf(-fabsf(a2))); \
    const float g2 = g4_2.C; \
    n2_##K = (g2 >= 0.0f && d2 >= 0.0f) ? fmaxf(g2 * 0.95f, d2) : g2; \
    lsum += (double)n2_##K; \
    const float a3 = accB_##K.y; \
    const float d3 = fmaxf(a3, 0.0f) + log1pf(expf(-fabsf(a3))); \
    const float g3 = g4_3.C; \
    n3_##K = (g3 >= 0.0f && d3 >= 0.0f) ? fmaxf(g3 * 0.95f, d3) : g3; \
    lsum += (double)n3_##K; }

    TAIL(0, x) TAIL(1, y) TAIL(2, z) TAIL(3, w)
#undef TAIL

    // ---- coalesced float4 stores (one dwordx4 per cascade) ----
    float4* o4 = (float4*)out;
    o4[(size_t)0 * (NCELLS / 4) + gid] = make_float4(n0_0, n0_1, n0_2, n0_3);
    o4[(size_t)1 * (NCELLS / 4) + gid] = make_float4(n1_0, n1_1, n1_2, n1_3);
    o4[(size_t)2 * (NCELLS / 4) + gid] = make_float4(n2_0, n2_1, n2_2, n2_3);
    o4[(size_t)3 * (NCELLS / 4) + gid] = make_float4(n3_0, n3_1, n3_2, n3_3);

    // wave-level f64 reduction -> 4 LDS partials -> one atomic per block
    #pragma unroll
    for (int s = 32; s > 0; s >>= 1) lsum += __shfl_down(lsum, s);
    const int wid = threadIdx.x >> 6;
    const int lane = threadIdx.x & 63;
    if (lane == 0) sdata[wid] = lsum;
    __syncthreads();
    if (threadIdx.x == 0)
        atomicAdd(sum_ws, (sdata[0] + sdata[1]) + (sdata[2] + sdata[3]));
}

__global__ void dg_finalize(const double* __restrict__ sum_ws,
                            float* __restrict__ out,
                            float* __restrict__ thr_ws)
{
    const double mean = *sum_ws / (double)GRID_TOTAL;
    const float mf = (float)mean;
    out[GRID_TOTAL] = mf;                 // mean_density output
    *thr_ws = fminf(mf, 2.0f);            // thresh for bitfield pass
}

// One thread per output byte: read 8 consecutive grid floats, pack bits, emit as float.
__global__ __launch_bounds__(256) void dg_bitfield(
    const float* __restrict__ grid,
    const float* __restrict__ thr_ws,
    float* __restrict__ outb)
{
    const int i = blockIdx.x * 256 + threadIdx.x;
    const float t = *thr_ws;
    const float4* p = (const float4*)(grid + (size_t)i * 8);
    const float4 a = p[0];
    const float4 b = p[1];
    int v = 0;
    v |= (a.x > t) ? 1   : 0;
    v |= (a.y > t) ? 2   : 0;
    v |= (a.z > t) ? 4   : 0;
    v |= (a.w > t) ? 8   : 0;
    v |= (b.x > t) ? 16  : 0;
    v |= (b.y > t) ? 32  : 0;
    v |= (b.z > t) ? 64  : 0;
    v |= (b.w > t) ? 128 : 0;
    outb[i] = (float)v;
}

extern "C" void kernel_launch(void* const* d_in, const int* in_sizes, int n_in,
                              void* d_out, int out_size, void* d_ws, size_t ws_size,
                              hipStream_t stream) {
    const float* dgrid = (const float*)d_in[0];
    const float* jit   = (const float*)d_in[1];
    const float* W1    = (const float*)d_in[2];
    const float* b1    = (const float*)d_in[3];
    const float* W2    = (const float*)d_in[4];
    const float* b2    = (const float*)d_in[5];

    float* out = (float*)d_out;
    double* sum_ws = (double*)d_ws;
    float* thr_ws = (float*)((char*)d_ws + 8);

    hipMemsetAsync(d_ws, 0, 8, stream);   // zero the f64 accumulator (capture-safe)

    dg_main<<<MAIN_BLOCKS, 256, 0, stream>>>(dgrid, jit, W1, b1, W2, b2, out, sum_ws);
    dg_finalize<<<1, 1, 0, stream>>>(sum_ws, out, thr_ws);
    dg_bitfield<<<NBYTES / 256, 256, 0, stream>>>(out, thr_ws, out + GRID_TOTAL + 1);
}

// Round 17
// 76.096 us; speedup vs baseline: 2.5851x; 1.0082x over previous
//
#include <hip/hip_runtime.h>

#define RES 128
#define NCELLS (RES * RES * RES)        // 2097152
#define CASC 4
#define GRID_TOTAL (CASC * NCELLS)      // 8388608 = 2^23
#define NBYTES (GRID_TOTAL / 8)         // 1048576
#define MAIN_BLOCKS (NCELLS / (256 * 4))     // 2048 (4 consecutive morton/thread)

typedef float f32x2 __attribute__((ext_vector_type(2)));

struct f3v { float x, y, z; };
__device__ __forceinline__ f3v load3(const float* __restrict__ p) {
    f3v v;
    __builtin_memcpy(&v, p, sizeof(f3v));   // -> global_load_dwordx3 (12B, 4B-aligned)
    return v;
}

// inverse of instant-ngp expand_bits: gather every 3rd bit
__device__ __forceinline__ unsigned compact3(unsigned v) {
    v &= 0x49249249u;
    v = (v | (v >> 2))  & 0xC30C30C3u;
    v = (v | (v >> 4))  & 0x0F00F00Fu;
    v = (v | (v >> 8))  & 0xFF0000FFu;
    v = (v | (v >> 16)) & 0x3FFu;
    return v;
}

__device__ __forceinline__ f32x2 pk_fma(f32x2 a, f32x2 b, f32x2 c) {
    return __builtin_elementwise_fma(a, b, c);   // v_pk_fma_f32, IEEE fma per lane
}

// 2048 blocks x 256 threads; thread gid handles morton m = gid*4 + {0,1,2,3}.
// Jitter: one dwordx3 per (point,cascade) -> 16 gather instrs/thread (was 48).
// dgrid/out as float4. j-outer weight loop (64 LDS reads). Math order unchanged.
__global__ __launch_bounds__(256) void dg_main(
    const float* __restrict__ dgrid,   // [CASC, NCELLS]
    const float* __restrict__ jit,     // [CASC, NCELLS, 3]
    const float* __restrict__ W1,      // [3,32]
    const float* __restrict__ b1,      // [32]
    const float* __restrict__ W2,      // [32]
    const float* __restrict__ b2,      // [1]
    float* __restrict__ out,           // [CASC, NCELLS]
    double* __restrict__ sum_ws)
{
    // wq[j] = {W1[j], W1[32+j], W1[64+j], b1[j]};  w2s[j] = W2[j]
    __shared__ float4 wq[32];
    __shared__ float w2s[32];
    __shared__ double sdata[4];
    if (threadIdx.x < 32) {
        const int j = threadIdx.x;
        wq[j] = make_float4(W1[j], W1[32 + j], W1[64 + j], b1[j]);
        w2s[j] = W2[j];
    }
    __syncthreads();

    const float bb2 = b2[0];
    const int gid = blockIdx.x * 256 + (int)threadIdx.x;   // float4-group index
    const int m0 = gid * 4;

    // ---- coalesced float4 dgrid loads (one dwordx4 per cascade) ----
    const float4* dg4 = (const float4*)dgrid;
    const float4 g4_0 = dg4[(size_t)0 * (NCELLS / 4) + gid];
    const float4 g4_1 = dg4[(size_t)1 * (NCELLS / 4) + gid];
    const float4 g4_2 = dg4[(size_t)2 * (NCELLS / 4) + gid];
    const float4 g4_3 = dg4[(size_t)3 * (NCELLS / 4) + gid];

    // ---- per-point coords, dwordx3 jitter loads, packed positions ----
#define PREP(K) \
    const int m_##K = m0 + K; \
    const unsigned x_##K = compact3((unsigned)m_##K); \
    const unsigned y_##K = compact3((unsigned)m_##K >> 1); \
    const unsigned z_##K = compact3((unsigned)m_##K >> 2); \
    const size_t jb_##K = ((size_t)((x_##K << 14) | (y_##K << 7) | z_##K)) * 3; \
    const float cx_##K = (float)x_##K, cy_##K = (float)y_##K, cz_##K = (float)z_##K; \
    const f3v ja_##K = load3(jit + jb_##K);                        /* cascade 0 */ \
    const f3v jb2_##K = load3(jit + (size_t)NCELLS * 3 + jb_##K);  /* cascade 1 */ \
    const f3v jc_##K = load3(jit + (size_t)NCELLS * 6 + jb_##K);   /* cascade 2 */ \
    const f3v jd_##K = load3(jit + (size_t)NCELLS * 9 + jb_##K);   /* cascade 3 */ \
    const f32x2 pxA_##K = { ((cx_##K + ja_##K.x) * (1.0f / 128.0f) - 0.5f) * 1.0f, \
                            ((cx_##K + jb2_##K.x) * (1.0f / 128.0f) - 0.5f) * 2.0f }; \
    const f32x2 pxB_##K = { ((cx_##K + jc_##K.x) * (1.0f / 128.0f) - 0.5f) * 4.0f, \
                            ((cx_##K + jd_##K.x) * (1.0f / 128.0f) - 0.5f) * 8.0f }; \
    const f32x2 pyA_##K = { ((cy_##K + ja_##K.y) * (1.0f / 128.0f) - 0.5f) * 1.0f, \
                            ((cy_##K + jb2_##K.y) * (1.0f / 128.0f) - 0.5f) * 2.0f }; \
    const f32x2 pyB_##K = { ((cy_##K + jc_##K.y) * (1.0f / 128.0f) - 0.5f) * 4.0f, \
                            ((cy_##K + jd_##K.y) * (1.0f / 128.0f) - 0.5f) * 8.0f }; \
    const f32x2 pzA_##K = { ((cz_##K + ja_##K.z) * (1.0f / 128.0f) - 0.5f) * 1.0f, \
                            ((cz_##K + jb2_##K.z) * (1.0f / 128.0f) - 0.5f) * 2.0f }; \
    const f32x2 pzB_##K = { ((cz_##K + jc_##K.z) * (1.0f / 128.0f) - 0.5f) * 4.0f, \
                            ((cz_##K + jd_##K.z) * (1.0f / 128.0f) - 0.5f) * 8.0f }; \
    f32x2 accA_##K = {bb2, bb2}, accB_##K = {bb2, bb2};

    PREP(0) PREP(1) PREP(2) PREP(3)
#undef PREP

    const f32x2 zer = {0.0f, 0.0f};

    // ---- j-outer MLP: one weight fetch per j feeds 8 chains (16 cells) ----
#define STEP(K) { \
        f32x2 hA = pk_fma(pxA_##K, wx, wb); \
        f32x2 hB = pk_fma(pxB_##K, wx, wb); \
        hA = pk_fma(pyA_##K, wy, hA); \
        hB = pk_fma(pyB_##K, wy, hB); \
        hA = pk_fma(pzA_##K, wz, hA); \
        hB = pk_fma(pzB_##K, wz, hB); \
        hA = __builtin_elementwise_max(hA, zer); \
        hB = __builtin_elementwise_max(hB, zer); \
        accA_##K = pk_fma(hA, uu, accA_##K); \
        accB_##K = pk_fma(hB, uu, accB_##K); }

    #pragma unroll 4
    for (int j = 0; j < 32; ++j) {
        const float4 w = wq[j];
        const float u = w2s[j];
        const f32x2 wx = {w.x, w.x}, wy = {w.y, w.y}, wz = {w.z, w.z};
        const f32x2 wb = {w.w, w.w}, uu = {u, u};
        STEP(0) STEP(1) STEP(2) STEP(3)
    }
#undef STEP

    double lsum = 0.0;
    float n0_0, n0_1, n0_2, n0_3;   // results: n<level>_<k>
    float n1_0, n1_1, n1_2, n1_3;
    float n2_0, n2_1, n2_2, n2_3;
    float n3_0, n3_1, n3_2, n3_3;

#define TAIL(K, C) { \
    const float a0 = accA_##K.x; \
    const float d0 = fmaxf(a0, 0.0f) + log1pf(expf(-fabsf(a0))); \
    const float g0 = g4_0.C; \
    n0_##K = (g0 >= 0.0f && d0 >= 0.0f) ? fmaxf(g0 * 0.95f, d0) : g0; \
    lsum += (double)n0_##K; \
    const float a1 = accA_##K.y; \
    const float d1 = fmaxf(a1, 0.0f) + log1pf(expf(-fabsf(a1))); \
    const float g1 = g4_1.C; \
    n1_##K = (g1 >= 0.0f && d1 >= 0.0f) ? fmaxf(g1 * 0.95f, d1) : g1; \
    lsum += (double)n1_##K; \
    const float a2 = accB_##K.x; \
    const float d2 = fmaxf(a2, 0.0f) + log1pf(expf(-fabsf(a2))); \
    const float g2 = g4_2.C; \
    n2_##K = (g2 >= 0.0f && d2 >= 0.0f) ? fmaxf(g2 * 0.95f, d2) : g2; \
    lsum += (double)n2_##K; \
    const float a3 = accB_##K.y; \
    const float d3 = fmaxf(a3, 0.0f) + log1pf(expf(-fabsf(a3))); \
    const float g3 = g4_3.C; \
    n3_##K = (g3 >= 0.0f && d3 >= 0.0f) ? fmaxf(g3 * 0.95f, d3) : g3; \
    lsum += (double)n3_##K; }

    TAIL(0, x) TAIL(1, y) TAIL(2, z) TAIL(3, w)
#undef TAIL

    // ---- coalesced float4 stores (one dwordx4 per cascade) ----
    float4* o4 = (float4*)out;
    o4[(size_t)0 * (NCELLS / 4) + gid] = make_float4(n0_0, n0_1, n0_2, n0_3);
    o4[(size_t)1 * (NCELLS / 4) + gid] = make_float4(n1_0, n1_1, n1_2, n1_3);
    o4[(size_t)2 * (NCELLS / 4) + gid] = make_float4(n2_0, n2_1, n2_2, n2_3);
    o4[(size_t)3 * (NCELLS / 4) + gid] = make_float4(n3_0, n3_1, n3_2, n3_3);

    // wave-level f64 reduction -> 4 LDS partials -> one atomic per block
    #pragma unroll
    for (int s = 32; s > 0; s >>= 1) lsum += __shfl_down(lsum, s);
    const int wid = threadIdx.x >> 6;
    const int lane = threadIdx.x & 63;
    if (lane == 0) sdata[wid] = lsum;
    __syncthreads();
    if (threadIdx.x == 0)
        atomicAdd(sum_ws, (sdata[0] + sdata[1]) + (sdata[2] + sdata[3]));
}

// One thread per output byte. Finalize folded in: mean = sum * 2^-23 is
// BIT-EXACT vs the former /GRID_TOTAL (power of two), computed per-thread
// from the f64 sum; block 0 thread 0 also writes the mean output.
__global__ __launch_bounds__(256) void dg_bitfield(
    const float* __restrict__ grid,
    const double* __restrict__ sum_ws,
    float* __restrict__ outb,
    float* __restrict__ mean_out)
{
    const int i = blockIdx.x * 256 + threadIdx.x;
    const double mean = *sum_ws * (1.0 / (double)GRID_TOTAL);   // exact: 2^-23
    const float mf = (float)mean;
    if (i == 0) mean_out[0] = mf;
    const float t = fminf(mf, 2.0f);
    const float4* p = (const float4*)(grid + (size_t)i * 8);
    const float4 a = p[0];
    const float4 b = p[1];
    int v = 0;
    v |= (a.x > t) ? 1   : 0;
    v |= (a.y > t) ? 2   : 0;
    v |= (a.z > t) ? 4   : 0;
    v |= (a.w > t) ? 8   : 0;
    v |= (b.x > t) ? 16  : 0;
    v |= (b.y > t) ? 32  : 0;
    v |= (b.z > t) ? 64  : 0;
    v |= (b.w > t) ? 128 : 0;
    outb[i] = (float)v;
}

extern "C" void kernel_launch(void* const* d_in, const int* in_sizes, int n_in,
                              void* d_out, int out_size, void* d_ws, size_t ws_size,
                              hipStream_t stream) {
    const float* dgrid = (const float*)d_in[0];
    const float* jit   = (const float*)d_in[1];
    const float* W1    = (const float*)d_in[2];
    const float* b1    = (const float*)d_in[3];
    const float* W2    = (const float*)d_in[4];
    const float* b2    = (const float*)d_in[5];

    float* out = (float*)d_out;
    double* sum_ws = (double*)d_ws;

    hipMemsetAsync(d_ws, 0, 8, stream);   // zero the f64 accumulator (capture-safe)

    dg_main<<<MAIN_BLOCKS, 256, 0, stream>>>(dgrid, jit, W1, b1, W2, b2, out, sum_ws);
    dg_bitfield<<<NBYTES / 256, 256, 0, stream>>>(out, sum_ws,
                                                  out + GRID_TOTAL + 1,
                                                  out + GRID_TOTAL);
}